// Round 4
// baseline (62.731 us; speedup 1.0000x reference)
//
#include <hip/hip_runtime.h>
#include <float.h>

#define C_    512
#define H_    38
#define W_    50
#define HW_   (H_ * W_)       // 1900
#define NROIS 1024
#define PS    7
#define PRE   14              // PS*2
#define NCELL 49              // PS*PS
#define CQ    128             // channels per block (quarter)
#define NGP   (PRE * PRE)     // 196 gridpoints

typedef float vfloat4 __attribute__((ext_vector_type(4)));

__device__ inline vfloat4 vmax4(vfloat4 a, vfloat4 b) {
    vfloat4 r;
    r.x = fmaxf(a.x, b.x); r.y = fmaxf(a.y, b.y);
    r.z = fmaxf(a.z, b.z); r.w = fmaxf(a.w, b.w);
    return r;
}

// ---------------------------------------------------------------------------
// Transpose bottom (C, H*W) -> (H*W, C) so corner gathers are coalesced
// across channels. 32x32 LDS tile transpose.
// ---------------------------------------------------------------------------
__global__ __launch_bounds__(256) void transpose_kernel(
    const float* __restrict__ in, float* __restrict__ out) {
    __shared__ float tile[32][33];
    const int pix0 = blockIdx.x * 32;
    const int c0   = blockIdx.y * 32;
    const int tx = threadIdx.x & 31;
    const int ty = threadIdx.x >> 5;

    for (int i = ty; i < 32; i += 8) {
        int c = c0 + i, pix = pix0 + tx;
        tile[i][tx] = (pix < HW_) ? in[c * HW_ + pix] : 0.0f;
    }
    __syncthreads();
    for (int i = ty; i < 32; i += 8) {
        int pix = pix0 + i, c = c0 + tx;
        if (pix < HW_) out[pix * C_ + c] = tile[tx][i];
    }
}

// ---------------------------------------------------------------------------
// Main crop-and-maxpool kernel (transposed src layout: src[pix*512 + c]).
// grid = NROIS*4; block = 256 (4 waves). Block (n,cq): ROI n, channels
// [cq*128, cq*128+128).
// Per cell: lanes 0-31 handle the cell's 2 top gridpoints (ry=0), lanes
// 32-63 the 2 bottom (ry=1); each lane loads float4 = 4 channels per corner
// -> 8 coalesced 1KB wave-loads/cell. Cross-half max via shfl_xor(32).
// Per-gridpoint corner offsets/weights precomputed once per block in LDS.
// ---------------------------------------------------------------------------
__global__ __launch_bounds__(256) void croppool_kernel(
    const float* __restrict__ src, const float* __restrict__ rois,
    float* __restrict__ out) {

    const int n  = blockIdx.x >> 2;
    const int cq = blockIdx.x & 3;
    const int cbase = cq * CQ;
    const int tid = threadIdx.x;

    __shared__ float outtile[CQ * NCELL];   // [c_local][cell], stride 49
    __shared__ int4   offt[NGP];            // 4 corner offsets (float elements)
    __shared__ float4 wgtt[NGP];            // 4 combined corner weights wy*wx

    // --- per-gridpoint tables (align_corners=True + zeros padding) ---
    if (tid < NGP) {
        const int gy = tid / PRE, gx = tid - PRE * gy;
        const float rx1 = rois[n * 5 + 1] * 0.0625f;
        const float ry1 = rois[n * 5 + 2] * 0.0625f;
        const float rx2 = rois[n * 5 + 3] * 0.0625f;
        const float ry2 = rois[n * 5 + 4] * 0.0625f;

        int xi0, xi1, yi0, yi1;
        float wx0, wx1, wy0, wy1;
        {   // x axis
            const float sz = (float)(W_ - 1);
            const float t0 = (rx2 - rx1) / sz, tc = (rx1 + rx2 - sz) / sz;
            const float base = -1.0f + (float)gx * (2.0f / 13.0f);
            const float coord = (t0 * base + tc + 1.0f) * 0.5f * sz;
            const float f = floorf(coord), a = coord - f;
            const int i0 = (int)f, i1 = i0 + 1;
            wx0 = (i0 >= 0 && i0 <= W_ - 1) ? (1.0f - a) : 0.0f;
            wx1 = (i1 >= 0 && i1 <= W_ - 1) ? a : 0.0f;
            xi0 = min(max(i0, 0), W_ - 1);
            xi1 = min(max(i1, 0), W_ - 1);
        }
        {   // y axis
            const float sz = (float)(H_ - 1);
            const float t0 = (ry2 - ry1) / sz, tc = (ry1 + ry2 - sz) / sz;
            const float base = -1.0f + (float)gy * (2.0f / 13.0f);
            const float coord = (t0 * base + tc + 1.0f) * 0.5f * sz;
            const float f = floorf(coord), a = coord - f;
            const int i0 = (int)f, i1 = i0 + 1;
            wy0 = (i0 >= 0 && i0 <= H_ - 1) ? (1.0f - a) : 0.0f;
            wy1 = (i1 >= 0 && i1 <= H_ - 1) ? a : 0.0f;
            yi0 = min(max(i0, 0), H_ - 1);
            yi1 = min(max(i1, 0), H_ - 1);
        }
        offt[tid] = make_int4((yi0 * W_ + xi0) * C_, (yi0 * W_ + xi1) * C_,
                              (yi1 * W_ + xi0) * C_, (yi1 * W_ + xi1) * C_);
        wgtt[tid] = make_float4(wy0 * wx0, wy0 * wx1, wy1 * wx0, wy1 * wx1);
    }
    __syncthreads();

    const int lane32 = tid & 31;         // channel group (4 ch each)
    const int half   = (tid >> 5) & 1;   // gridpoint row within cell
    const int wave   = tid >> 6;
    const float* srcc = src + cbase + 4 * lane32;

    for (int cell = wave; cell < NCELL; cell += 4) {
        const int py = cell / PS, px = cell - PS * py;
        const int gp = (2 * py + half) * PRE + 2 * px;

        const int4   oA = offt[gp],     oB = offt[gp + 1];
        const float4 wA = wgtt[gp],     wB = wgtt[gp + 1];

        const vfloat4 pA0 = *(const vfloat4*)(srcc + oA.x);
        const vfloat4 pA1 = *(const vfloat4*)(srcc + oA.y);
        const vfloat4 pA2 = *(const vfloat4*)(srcc + oA.z);
        const vfloat4 pA3 = *(const vfloat4*)(srcc + oA.w);
        const vfloat4 pB0 = *(const vfloat4*)(srcc + oB.x);
        const vfloat4 pB1 = *(const vfloat4*)(srcc + oB.y);
        const vfloat4 pB2 = *(const vfloat4*)(srcc + oB.z);
        const vfloat4 pB3 = *(const vfloat4*)(srcc + oB.w);

        const vfloat4 vA = wA.x * pA0 + wA.y * pA1 + wA.z * pA2 + wA.w * pA3;
        const vfloat4 vB = wB.x * pB0 + wB.y * pB1 + wB.z * pB2 + wB.w * pB3;
        vfloat4 m = vmax4(vA, vB);

        // combine across the two halves (ry=0 vs ry=1)
        #pragma unroll
        for (int j = 0; j < 4; ++j) {
            float v = m[j];
            m[j] = fmaxf(v, __shfl_xor(v, 32, 64));
        }

        // every lane writes 2 of its 4 channels (halves split j-pairs)
        const int ch = 4 * lane32 + 2 * half;
        outtile[(ch    ) * NCELL + cell] = m[2 * half];
        outtile[(ch + 1) * NCELL + cell] = m[2 * half + 1];
    }
    __syncthreads();

    // --- flush: LDS tile IS the output sub-block layout -> contiguous 16B nt stores ---
    const vfloat4* lsrc = (const vfloat4*)outtile;
    vfloat4* dst = (vfloat4*)out + (size_t)n * (C_ * NCELL / 4) + cq * (CQ * NCELL / 4);
    for (int i = tid; i < CQ * NCELL / 4; i += 256) {
        __builtin_nontemporal_store(lsrc[i], &dst[i]);
    }
}

// ---------------------------------------------------------------------------
// Fallback (reads original (C,H*W) layout directly) — only if d_ws too small.
// ---------------------------------------------------------------------------
__global__ __launch_bounds__(256) void croppool_fallback(
    const float* __restrict__ src, const float* __restrict__ rois,
    float* __restrict__ out) {

    const int n  = blockIdx.x >> 2;
    const int cq = blockIdx.x & 3;
    const int cbase = cq * CQ;
    const int tid = threadIdx.x;

    __shared__ float outtile[CQ * NCELL];
    __shared__ int   xi0[PRE], xi1[PRE], yi0[PRE], yi1[PRE];
    __shared__ float xw0[PRE], xw1[PRE], yw0[PRE], yw1[PRE];

    if (tid < 2 * PRE) {
        const int  j   = tid % PRE;
        const bool isy = tid >= PRE;
        const float r1 = rois[n * 5 + (isy ? 2 : 1)] * 0.0625f;
        const float r2 = rois[n * 5 + (isy ? 4 : 3)] * 0.0625f;
        const float sz = isy ? (float)(H_ - 1) : (float)(W_ - 1);
        const int  szi = isy ? (H_ - 1) : (W_ - 1);
        const float t0 = (r2 - r1) / sz;
        const float tc = (r1 + r2 - sz) / sz;
        const float base = -1.0f + (float)j * (2.0f / 13.0f);
        const float coord = (t0 * base + tc + 1.0f) * 0.5f * sz;
        const float f = floorf(coord);
        const float a = coord - f;
        const int i0 = (int)f;
        const int i1 = i0 + 1;
        const float w0 = (i0 >= 0 && i0 <= szi) ? (1.0f - a) : 0.0f;
        const float w1 = (i1 >= 0 && i1 <= szi) ? a : 0.0f;
        const int i0c = min(max(i0, 0), szi);
        const int i1c = min(max(i1, 0), szi);
        if (isy) { yi0[j] = i0c; yi1[j] = i1c; yw0[j] = w0; yw1[j] = w1; }
        else     { xi0[j] = i0c; xi1[j] = i1c; xw0[j] = w0; xw1[j] = w1; }
    }
    __syncthreads();

    const int wave = tid >> 6;
    const int lane = tid & 63;
    const float* srcc = src + (size_t)(cbase + lane) * HW_;

    for (int cell = wave; cell < NCELL; cell += 4) {
        const int py = cell / PS, px = cell % PS;
        float m0 = -FLT_MAX, m1 = -FLT_MAX;
        for (int ry = 0; ry < 2; ++ry) {
            const int gy = 2 * py + ry;
            for (int rx = 0; rx < 2; ++rx) {
                const int gx = 2 * px + rx;
                const int i00 = yi0[gy] * W_ + xi0[gx], i01 = yi0[gy] * W_ + xi1[gx];
                const int i10 = yi1[gy] * W_ + xi0[gx], i11 = yi1[gy] * W_ + xi1[gx];
                const float v0 = yw0[gy] * (xw0[gx] * srcc[i00] + xw1[gx] * srcc[i01])
                               + yw1[gy] * (xw0[gx] * srcc[i10] + xw1[gx] * srcc[i11]);
                const float v1 = yw0[gy] * (xw0[gx] * srcc[64 * HW_ + i00] + xw1[gx] * srcc[64 * HW_ + i01])
                               + yw1[gy] * (xw0[gx] * srcc[64 * HW_ + i10] + xw1[gx] * srcc[64 * HW_ + i11]);
                m0 = fmaxf(m0, v0);
                m1 = fmaxf(m1, v1);
            }
        }
        outtile[lane * NCELL + cell]        = m0;
        outtile[(lane + 64) * NCELL + cell] = m1;
    }
    __syncthreads();

    const vfloat4* lsrc = (const vfloat4*)outtile;
    vfloat4* dst = (vfloat4*)out + (size_t)n * (C_ * NCELL / 4) + cq * (CQ * NCELL / 4);
    for (int i = tid; i < CQ * NCELL / 4; i += 256) {
        __builtin_nontemporal_store(lsrc[i], &dst[i]);
    }
}

extern "C" void kernel_launch(void* const* d_in, const int* in_sizes, int n_in,
                              void* d_out, int out_size, void* d_ws, size_t ws_size,
                              hipStream_t stream) {
    const float* bottom = (const float*)d_in[0];   // (1, 512, 38, 50)
    const float* rois   = (const float*)d_in[1];   // (1024, 5)
    float* out = (float*)d_out;                    // (1024, 512, 7, 7)

    const size_t trans_bytes = (size_t)HW_ * C_ * sizeof(float);
    if (ws_size >= trans_bytes) {
        float* trans = (float*)d_ws;
        dim3 tgrid((HW_ + 31) / 32, C_ / 32);
        transpose_kernel<<<tgrid, 256, 0, stream>>>(bottom, trans);
        croppool_kernel<<<NROIS * 4, 256, 0, stream>>>(trans, rois, out);
    } else {
        croppool_fallback<<<NROIS * 4, 256, 0, stream>>>(bottom, rois, out);
    }
}

// Round 8
// 60.823 us; speedup vs baseline: 1.0314x; 1.0314x over previous
//
#include <hip/hip_runtime.h>
#include <hip/hip_fp16.h>
#include <float.h>

#define C_    512
#define H_    38
#define W_    50
#define HW_   (H_ * W_)       // 1900
#define NROIS 1024
#define PS    7
#define PRE   14              // PS*2
#define NCELL 49              // PS*PS
#define CQ    128             // channels per block (quarter)
#define NGP   (PRE * PRE)     // 196 gridpoints

typedef float vfloat4 __attribute__((ext_vector_type(4)));
typedef _Float16 h2 __attribute__((ext_vector_type(2)));

// ---------------------------------------------------------------------------
// Transpose + downconvert: bottom (C, H*W) f32 -> (H*W, C) fp16.
// ---------------------------------------------------------------------------
__global__ __launch_bounds__(256) void transpose_kernel(
    const float* __restrict__ in, _Float16* __restrict__ out) {
    __shared__ float tile[32][33];
    const int pix0 = blockIdx.x * 32;
    const int c0   = blockIdx.y * 32;
    const int tx = threadIdx.x & 31;
    const int ty = threadIdx.x >> 5;

    for (int i = ty; i < 32; i += 8) {
        int c = c0 + i, pix = pix0 + tx;
        tile[i][tx] = (pix < HW_) ? in[c * HW_ + pix] : 0.0f;
    }
    __syncthreads();
    for (int i = ty; i < 32; i += 8) {
        int pix = pix0 + i, c = c0 + tx;
        if (pix < HW_) out[pix * C_ + c] = (_Float16)tile[tx][i];
    }
}

// ---------------------------------------------------------------------------
// Main crop-and-maxpool kernel (transposed fp16 src: src[pix*512 + c]).
// grid = NROIS*4; block = 256 (4 waves). Block (n,cq): ROI n, channels
// [cq*128, cq*128+128). Lanes 0-31 handle the cell's top 2 gridpoints,
// lanes 32-63 the bottom 2; each lane loads 4 fp16 channels (8B) per corner.
// Bilinear + max in packed fp16; cross-half max via shfl_xor(32).
// ---------------------------------------------------------------------------
__global__ __launch_bounds__(256) void croppool_kernel(
    const _Float16* __restrict__ src, const float* __restrict__ rois,
    float* __restrict__ out) {

    const int n  = blockIdx.x >> 2;
    const int cq = blockIdx.x & 3;
    const int cbase = cq * CQ;
    const int tid = threadIdx.x;

    __shared__ float outtile[CQ * NCELL];   // [c_local][cell], stride 49
    __shared__ int4  offt[NGP];             // 4 corner offsets (half elements)
    __shared__ h2    wgtt[NGP][4];          // 4 corner weights, duplicated

    // --- per-gridpoint tables (align_corners=True + zeros padding) ---
    if (tid < NGP) {
        const int gy = tid / PRE, gx = tid - PRE * gy;
        const float rx1 = rois[n * 5 + 1] * 0.0625f;
        const float ry1 = rois[n * 5 + 2] * 0.0625f;
        const float rx2 = rois[n * 5 + 3] * 0.0625f;
        const float ry2 = rois[n * 5 + 4] * 0.0625f;

        int xi0, xi1, yi0, yi1;
        float wx0, wx1, wy0, wy1;
        {   // x axis
            const float sz = (float)(W_ - 1);
            const float t0 = (rx2 - rx1) / sz, tc = (rx1 + rx2 - sz) / sz;
            const float base = -1.0f + (float)gx * (2.0f / 13.0f);
            const float coord = (t0 * base + tc + 1.0f) * 0.5f * sz;
            const float f = floorf(coord), a = coord - f;
            const int i0 = (int)f, i1 = i0 + 1;
            wx0 = (i0 >= 0 && i0 <= W_ - 1) ? (1.0f - a) : 0.0f;
            wx1 = (i1 >= 0 && i1 <= W_ - 1) ? a : 0.0f;
            xi0 = min(max(i0, 0), W_ - 1);
            xi1 = min(max(i1, 0), W_ - 1);
        }
        {   // y axis
            const float sz = (float)(H_ - 1);
            const float t0 = (ry2 - ry1) / sz, tc = (ry1 + ry2 - sz) / sz;
            const float base = -1.0f + (float)gy * (2.0f / 13.0f);
            const float coord = (t0 * base + tc + 1.0f) * 0.5f * sz;
            const float f = floorf(coord), a = coord - f;
            const int i0 = (int)f, i1 = i0 + 1;
            wy0 = (i0 >= 0 && i0 <= H_ - 1) ? (1.0f - a) : 0.0f;
            wy1 = (i1 >= 0 && i1 <= H_ - 1) ? a : 0.0f;
            yi0 = min(max(i0, 0), H_ - 1);
            yi1 = min(max(i1, 0), H_ - 1);
        }
        offt[tid] = make_int4((yi0 * W_ + xi0) * C_, (yi0 * W_ + xi1) * C_,
                              (yi1 * W_ + xi0) * C_, (yi1 * W_ + xi1) * C_);
        const _Float16 w0 = (_Float16)(wy0 * wx0);
        const _Float16 w1 = (_Float16)(wy0 * wx1);
        const _Float16 w2 = (_Float16)(wy1 * wx0);
        const _Float16 w3 = (_Float16)(wy1 * wx1);
        wgtt[tid][0] = (h2){w0, w0};
        wgtt[tid][1] = (h2){w1, w1};
        wgtt[tid][2] = (h2){w2, w2};
        wgtt[tid][3] = (h2){w3, w3};
    }
    __syncthreads();

    const int lane32 = tid & 31;         // channel group (4 ch each)
    const int half_  = (tid >> 5) & 1;   // gridpoint row within cell
    const int wave   = tid >> 6;
    const _Float16* srcc = src + cbase + 4 * lane32;

    for (int cell = wave; cell < NCELL; cell += 4) {
        const int py = cell / PS, px = cell - PS * py;
        const int gp = (2 * py + half_) * PRE + 2 * px;

        const int4 oA = offt[gp], oB = offt[gp + 1];
        const h2 wA0 = wgtt[gp][0],     wA1 = wgtt[gp][1];
        const h2 wA2 = wgtt[gp][2],     wA3 = wgtt[gp][3];
        const h2 wB0 = wgtt[gp + 1][0], wB1 = wgtt[gp + 1][1];
        const h2 wB2 = wgtt[gp + 1][2], wB3 = wgtt[gp + 1][3];

        const uint2 A0 = *(const uint2*)(srcc + oA.x);
        const uint2 A1 = *(const uint2*)(srcc + oA.y);
        const uint2 A2 = *(const uint2*)(srcc + oA.z);
        const uint2 A3 = *(const uint2*)(srcc + oA.w);
        const uint2 B0 = *(const uint2*)(srcc + oB.x);
        const uint2 B1 = *(const uint2*)(srcc + oB.y);
        const uint2 B2 = *(const uint2*)(srcc + oB.z);
        const uint2 B3 = *(const uint2*)(srcc + oB.w);

        h2 vAl = wA0 * __builtin_bit_cast(h2, A0.x)
               + wA1 * __builtin_bit_cast(h2, A1.x)
               + wA2 * __builtin_bit_cast(h2, A2.x)
               + wA3 * __builtin_bit_cast(h2, A3.x);
        h2 vAh = wA0 * __builtin_bit_cast(h2, A0.y)
               + wA1 * __builtin_bit_cast(h2, A1.y)
               + wA2 * __builtin_bit_cast(h2, A2.y)
               + wA3 * __builtin_bit_cast(h2, A3.y);
        h2 vBl = wB0 * __builtin_bit_cast(h2, B0.x)
               + wB1 * __builtin_bit_cast(h2, B1.x)
               + wB2 * __builtin_bit_cast(h2, B2.x)
               + wB3 * __builtin_bit_cast(h2, B3.x);
        h2 vBh = wB0 * __builtin_bit_cast(h2, B0.y)
               + wB1 * __builtin_bit_cast(h2, B1.y)
               + wB2 * __builtin_bit_cast(h2, B2.y)
               + wB3 * __builtin_bit_cast(h2, B3.y);

        h2 mlo = __builtin_elementwise_max(vAl, vBl);
        h2 mhi = __builtin_elementwise_max(vAh, vBh);

        // combine across the two halves (ry=0 vs ry=1)
        {
            int t = __shfl_xor(__builtin_bit_cast(int, mlo), 32, 64);
            mlo = __builtin_elementwise_max(mlo, __builtin_bit_cast(h2, t));
            t = __shfl_xor(__builtin_bit_cast(int, mhi), 32, 64);
            mhi = __builtin_elementwise_max(mhi, __builtin_bit_cast(h2, t));
        }

        // every lane writes 2 of its 4 channels (halves split pairs)
        const h2 sel = half_ ? mhi : mlo;
        const int ch = 4 * lane32 + 2 * half_;
        outtile[(ch    ) * NCELL + cell] = (float)sel.x;
        outtile[(ch + 1) * NCELL + cell] = (float)sel.y;
    }
    __syncthreads();

    // --- flush: LDS tile IS the output sub-block layout -> contiguous 16B nt stores ---
    const vfloat4* lsrc = (const vfloat4*)outtile;
    vfloat4* dst = (vfloat4*)out + (size_t)n * (C_ * NCELL / 4) + cq * (CQ * NCELL / 4);
    for (int i = tid; i < CQ * NCELL / 4; i += 256) {
        __builtin_nontemporal_store(lsrc[i], &dst[i]);
    }
}

// ---------------------------------------------------------------------------
// Fallback (reads original (C,H*W) f32 layout directly) — only if d_ws tiny.
// ---------------------------------------------------------------------------
__global__ __launch_bounds__(256) void croppool_fallback(
    const float* __restrict__ src, const float* __restrict__ rois,
    float* __restrict__ out) {

    const int n  = blockIdx.x >> 2;
    const int cq = blockIdx.x & 3;
    const int cbase = cq * CQ;
    const int tid = threadIdx.x;

    __shared__ float outtile[CQ * NCELL];
    __shared__ int   xi0[PRE], xi1[PRE], yi0[PRE], yi1[PRE];
    __shared__ float xw0[PRE], xw1[PRE], yw0[PRE], yw1[PRE];

    if (tid < 2 * PRE) {
        const int  j   = tid % PRE;
        const bool isy = tid >= PRE;
        const float r1 = rois[n * 5 + (isy ? 2 : 1)] * 0.0625f;
        const float r2 = rois[n * 5 + (isy ? 4 : 3)] * 0.0625f;
        const float sz = isy ? (float)(H_ - 1) : (float)(W_ - 1);
        const int  szi = isy ? (H_ - 1) : (W_ - 1);
        const float t0 = (r2 - r1) / sz;
        const float tc = (r1 + r2 - sz) / sz;
        const float base = -1.0f + (float)j * (2.0f / 13.0f);
        const float coord = (t0 * base + tc + 1.0f) * 0.5f * sz;
        const float f = floorf(coord);
        const float a = coord - f;
        const int i0 = (int)f;
        const int i1 = i0 + 1;
        const float w0 = (i0 >= 0 && i0 <= szi) ? (1.0f - a) : 0.0f;
        const float w1 = (i1 >= 0 && i1 <= szi) ? a : 0.0f;
        const int i0c = min(max(i0, 0), szi);
        const int i1c = min(max(i1, 0), szi);
        if (isy) { yi0[j] = i0c; yi1[j] = i1c; yw0[j] = w0; yw1[j] = w1; }
        else     { xi0[j] = i0c; xi1[j] = i1c; xw0[j] = w0; xw1[j] = w1; }
    }
    __syncthreads();

    const int wave = tid >> 6;
    const int lane = tid & 63;
    const float* srcc = src + (size_t)(cbase + lane) * HW_;

    for (int cell = wave; cell < NCELL; cell += 4) {
        const int py = cell / PS, px = cell % PS;
        float m0 = -FLT_MAX, m1 = -FLT_MAX;
        for (int ry = 0; ry < 2; ++ry) {
            const int gy = 2 * py + ry;
            for (int rx = 0; rx < 2; ++rx) {
                const int gx = 2 * px + rx;
                const int i00 = yi0[gy] * W_ + xi0[gx], i01 = yi0[gy] * W_ + xi1[gx];
                const int i10 = yi1[gy] * W_ + xi0[gx], i11 = yi1[gy] * W_ + xi1[gx];
                const float v0 = yw0[gy] * (xw0[gx] * srcc[i00] + xw1[gx] * srcc[i01])
                               + yw1[gy] * (xw0[gx] * srcc[i10] + xw1[gx] * srcc[i11]);
                const float v1 = yw0[gy] * (xw0[gx] * srcc[64 * HW_ + i00] + xw1[gx] * srcc[64 * HW_ + i01])
                               + yw1[gy] * (xw0[gx] * srcc[64 * HW_ + i10] + xw1[gx] * srcc[64 * HW_ + i11]);
                m0 = fmaxf(m0, v0);
                m1 = fmaxf(m1, v1);
            }
        }
        outtile[lane * NCELL + cell]        = m0;
        outtile[(lane + 64) * NCELL + cell] = m1;
    }
    __syncthreads();

    const vfloat4* lsrc = (const vfloat4*)outtile;
    vfloat4* dst = (vfloat4*)out + (size_t)n * (C_ * NCELL / 4) + cq * (CQ * NCELL / 4);
    for (int i = tid; i < CQ * NCELL / 4; i += 256) {
        __builtin_nontemporal_store(lsrc[i], &dst[i]);
    }
}

extern "C" void kernel_launch(void* const* d_in, const int* in_sizes, int n_in,
                              void* d_out, int out_size, void* d_ws, size_t ws_size,
                              hipStream_t stream) {
    const float* bottom = (const float*)d_in[0];   // (1, 512, 38, 50)
    const float* rois   = (const float*)d_in[1];   // (1024, 5)
    float* out = (float*)d_out;                    // (1024, 512, 7, 7)

    const size_t trans_bytes = (size_t)HW_ * C_ * sizeof(_Float16);
    if (ws_size >= trans_bytes) {
        _Float16* trans = (_Float16*)d_ws;
        dim3 tgrid((HW_ + 31) / 32, C_ / 32);
        transpose_kernel<<<tgrid, 256, 0, stream>>>(bottom, trans);
        croppool_kernel<<<NROIS * 4, 256, 0, stream>>>(trans, rois, out);
    } else {
        croppool_fallback<<<NROIS * 4, 256, 0, stream>>>(bottom, rois, out);
    }
}